// Round 15
// baseline (1783.976 us; speedup 1.0000x reference)
//
#include <hip/hip_runtime.h>

#define H 128
#define NATOM 50000
#define NEDGE 800000

typedef __attribute__((ext_vector_type(8))) short short8;
typedef __attribute__((ext_vector_type(4))) float f32x4;
typedef __attribute__((ext_vector_type(4))) unsigned int uint4n;  // NT-store-compatible

#define MFMA16(a, b, c) __builtin_amdgcn_mfma_f32_16x16x32_bf16((a), (b), (c), 0, 0, 0)

__device__ __forceinline__ unsigned short f2b(float f) {
  unsigned int u = __float_as_uint(f);
  unsigned int r = (u + 0x7FFFu + ((u >> 16) & 1u)) >> 16;
  return (unsigned short)r;
}
__device__ __forceinline__ float b2f(unsigned short b) {
  return __uint_as_float(((unsigned int)b) << 16);
}

// Packed f32x2 -> bf16x2 (RNE). gfx950 v_cvt_pk_bf16_f32 = 1 inst vs ~8 for
// two manual RNE converts; guarded so a missing builtin can't break compile.
#if __has_builtin(__builtin_amdgcn_cvt_pk_bf16_f32)
__device__ __forceinline__ unsigned int f2b2(float lo, float hi) {
  typedef __bf16 bf16x2 __attribute__((ext_vector_type(2)));
  bf16x2 r = __builtin_amdgcn_cvt_pk_bf16_f32(lo, hi);
  union { bf16x2 v; unsigned int u; } c;
  c.v = r;
  return c.u;
}
#else
__device__ __forceinline__ unsigned int f2b2(float lo, float hi) {
  return (unsigned int)f2b(lo) | ((unsigned int)f2b(hi) << 16);
}
#endif

// Fast silu: hardware rcp (~1e-5 rel err, far below bf16 lsb).
__device__ __forceinline__ float silu_f(float x) {
  return x * __builtin_amdgcn_rcpf(1.0f + __expf(-x));
}

// ---------------------------------------------------------------------------
// Weight repack: f32 [128][128] row-major -> bf16 MFMA B-fragment layout.
// ---------------------------------------------------------------------------
struct PackSrc { const float* p[24]; };

__global__ void repack_kernel(PackSrc ps, unsigned short* __restrict__ dst) {
  const float* src = ps.p[blockIdx.x];
  unsigned short* d = dst + (size_t)blockIdx.x * 16384;
  for (int s = threadIdx.x; s < 2048; s += 256) {
    const int ct = s >> 8;
    const int kc = (s >> 6) & 3;
    const int lane = s & 63;
    const int r0 = kc * 32 + (lane >> 4) * 8;
    const int col = ct * 16 + (lane & 15);
    uint4 u;
    u.x = f2b2(src[(r0 + 0) * H + col], src[(r0 + 1) * H + col]);
    u.y = f2b2(src[(r0 + 2) * H + col], src[(r0 + 3) * H + col]);
    u.z = f2b2(src[(r0 + 4) * H + col], src[(r0 + 5) * H + col]);
    u.w = f2b2(src[(r0 + 6) * H + col], src[(r0 + 7) * H + col]);
    *(uint4*)(d + s * 8) = u;
  }
}

__global__ void embed_kernel(const int* __restrict__ atom_num, const float* __restrict__ emb,
                             unsigned short* __restrict__ h0) {
  const int idx = blockIdx.x * 256 + threadIdx.x;  // over NATOM*64
  const int n = idx >> 6;
  const int c = (idx & 63) * 2;
  const float* src = emb + (size_t)atom_num[n] * H + c;
  *(unsigned int*)(h0 + (size_t)n * H + c) = f2b2(src[0], src[1]);
}

__global__ void zero_int_kernel(int4* __restrict__ p, int n4) {
  const int i = blockIdx.x * 256 + threadIdx.x;
  if (i < n4) p[i] = make_int4(0, 0, 0, 0);
}

// ---------------------------------------------------------------------------
// CSR build. cell = (e/CE)*NATOM + atom (chunk-major). Built once per launch.
// ---------------------------------------------------------------------------
__global__ void count_kernel(const int* __restrict__ u1, const int* __restrict__ v1,
                             const int* __restrict__ u2, const int* __restrict__ v2,
                             int* __restrict__ deg1, int* __restrict__ deg2,
                             int CE) {
  const int e = blockIdx.x * 256 + threadIdx.x;
  const int cb = (e / CE) * NATOM;
  atomicAdd(deg1 + cb + u1[e], 1);
  atomicAdd(deg1 + cb + v1[e], 1);
  atomicAdd(deg2 + cb + u2[e], 1);
  atomicAdd(deg2 + cb + v2[e], 1);
}

// 3-phase parallel scan.
__global__ void scan_phase1(const int* __restrict__ deg, int* __restrict__ partials,
                            int ncells) {
  __shared__ int sh[256];
  const int t = threadIdx.x;
  const int base = blockIdx.x * 1024 + t * 4;
  int s = 0;
#pragma unroll
  for (int j = 0; j < 4; ++j) { const int i = base + j; if (i < ncells) s += deg[i]; }
  sh[t] = s;
  __syncthreads();
  for (int off = 128; off > 0; off >>= 1) {
    if (t < off) sh[t] += sh[t + off];
    __syncthreads();
  }
  if (t == 0) partials[blockIdx.x] = sh[0];
}

__global__ void scan_phase2(int* __restrict__ partials, int np) {
  __shared__ int sh[1024];
  const int t = threadIdx.x;
  const int v = t < np ? partials[t] : 0;
  sh[t] = v;
  __syncthreads();
  for (int off = 1; off < 1024; off <<= 1) {
    int x = 0;
    if (t >= off) x = sh[t - off];
    __syncthreads();
    sh[t] += x;
    __syncthreads();
  }
  if (t < np) partials[t] = sh[t] - v;  // exclusive
}

__global__ void scan_phase3(const int* __restrict__ deg, const int* __restrict__ partials,
                            int* __restrict__ start, int* __restrict__ cursor, int ncells) {
  __shared__ int sh[256];
  const int t = threadIdx.x;
  const int base = blockIdx.x * 1024 + t * 4;
  int v[4];
  int s = 0;
#pragma unroll
  for (int j = 0; j < 4; ++j) {
    const int i = base + j;
    v[j] = (i < ncells) ? deg[i] : 0;
    s += v[j];
  }
  sh[t] = s;
  __syncthreads();
  const int own = s;
  for (int off = 1; off < 256; off <<= 1) {
    int x = 0;
    if (t >= off) x = sh[t - off];
    __syncthreads();
    sh[t] += x;
    __syncthreads();
  }
  int o = partials[blockIdx.x] + sh[t] - own;
#pragma unroll
  for (int j = 0; j < 4; ++j) {
    const int i = base + j;
    if (i < ncells) {
      start[i] = o;
      cursor[i] = o;
      o += v[j];
      if (i == ncells - 1) start[ncells] = o;
    }
  }
}

// Range-bucketed fill with NT id loads. npass=4 (was 8): with NT loads the
// active list region (1.6MB, ~200KB/XCD) still stays L2-resident, and the
// id re-read stream halves (102->51MB).
__global__ void fill_kernel(const int* __restrict__ u1, const int* __restrict__ v1,
                            const int* __restrict__ u2, const int* __restrict__ v2,
                            int* __restrict__ cur1, int* __restrict__ cur2,
                            int* __restrict__ list1, int* __restrict__ list2,
                            int CE, int npass) {
  const int apb = (NATOM + npass - 1) / npass;
  for (int p = 0; p < npass; ++p) {
    const int lo = p * apb, hi = lo + apb;
    for (int e = blockIdx.x * 256 + threadIdx.x; e < NEDGE; e += gridDim.x * 256) {
      const int cb = (e / CE) * NATOM;
      int a;
      a = __builtin_nontemporal_load(u1 + e);
      if (a >= lo && a < hi) { const int s = atomicAdd(cur1 + cb + a, 1); list1[s] = e; }
      a = __builtin_nontemporal_load(v1 + e);
      if (a >= lo && a < hi) { const int s = atomicAdd(cur1 + cb + a, 1); list1[s] = e; }
      a = __builtin_nontemporal_load(u2 + e);
      if (a >= lo && a < hi) { const int s = atomicAdd(cur2 + cb + a, 1); list2[s] = e; }
      a = __builtin_nontemporal_load(v2 + e);
      if (a >= lo && a < hi) { const int s = atomicAdd(cur2 + cb + a, 1); list2[s] = e; }
    }
  }
}

// ---------------------------------------------------------------------------
// Fused edge MLP — round-7 structure + fast epilogues (measured 252us,
// VALUBusy 33.7, MfmaUtil 18; the residual ~48% stall is the 4-barrier
// K-loop's structural drain at 2 blocks/CU — 5 restructures all regressed).
// ---------------------------------------------------------------------------
__global__ __launch_bounds__(256, 2)
void edge_kernel(const unsigned short* __restrict__ h,
                 const int* __restrict__ idu, const int* __restrict__ idv,
                 const float* __restrict__ dis,
                 const unsigned short* __restrict__ pWu, const unsigned short* __restrict__ pWv,
                 const unsigned short* __restrict__ pW2, const unsigned short* __restrict__ pW3,
                 const float* __restrict__ Wdis, const float* __restrict__ b1,
                 const float* __restrict__ b2, const float* __restrict__ b3,
                 unsigned short* __restrict__ msg, int eBase, int nTiles) {
  __shared__ __attribute__((aligned(16))) unsigned short sA[2][64][136];
  __shared__ __attribute__((aligned(16))) unsigned short sB[2][64][136];
  __shared__ float sDis[2][64];

  const int tid = threadIdx.x;
  const int wave = tid >> 6;
  const int lane = tid & 63;
  const int l15 = lane & 15;
  const int quad = lane >> 4;

  short8 wWu[2][4], wWv[2][4], wW2[2][4], wW3[2][4];
#pragma unroll
  for (int ct = 0; ct < 2; ++ct) {
#pragma unroll
    for (int kc = 0; kc < 4; ++kc) {
      const int off = (((wave * 2 + ct) * 4 + kc) * 64 + lane) * 8;
      wWu[ct][kc] = *(const short8*)(pWu + off);
      wWv[ct][kc] = *(const short8*)(pWv + off);
      wW2[ct][kc] = *(const short8*)(pW2 + off);
      wW3[ct][kc] = *(const short8*)(pW3 + off);
    }
  }
  float vWd[2], vb1[2], vb2[2], vb3[2];
#pragma unroll
  for (int ct = 0; ct < 2; ++ct) {
    const int col = wave * 32 + ct * 16 + l15;
    vWd[ct] = Wdis[col]; vb1[ct] = b1[col]; vb2[ct] = b2[col]; vb3[ct] = b3[col];
  }

  const int stride = gridDim.x;
  const int r0 = tid >> 4;
  const int ch = tid & 15;
  int tile = blockIdx.x;
  int cur = 0;

  if (tile < nTiles) {  // prologue: stage tile -> buf0
    const int e0 = eBase + tile * 64;
    if (tid < 64) sDis[0][tid] = dis[e0 + tid];
#pragma unroll
    for (int it = 0; it < 4; ++it) {
      const int rr = r0 + it * 16;
      *(uint4*)(&sA[0][rr][ch * 8]) = *(const uint4*)(h + (size_t)idu[e0 + rr] * H + ch * 8);
      *(uint4*)(&sB[0][rr][ch * 8]) = *(const uint4*)(h + (size_t)idv[e0 + rr] * H + ch * 8);
    }
  }
  __syncthreads();

  for (; tile < nTiles; tile += stride, cur ^= 1) {
    const int nxt = cur ^ 1;
    const int tileN = tile + stride;
    const bool hasNext = tileN < nTiles;
    uint4 pfA[4], pfB[4];
    float pfD = 0.f;
    if (hasNext) {  // issue next tile's gathers (landed after b1)
      const int e0n = eBase + tileN * 64;
      if (tid < 64) pfD = dis[e0n + tid];
#pragma unroll
      for (int it = 0; it < 4; ++it) {
        const int rr = r0 + it * 16;
        pfA[it] = *(const uint4*)(h + (size_t)idu[e0n + rr] * H + ch * 8);
        pfB[it] = *(const uint4*)(h + (size_t)idv[e0n + rr] * H + ch * 8);
      }
    }

    f32x4 acc[4][2];
#pragma unroll
    for (int rt = 0; rt < 4; ++rt)
#pragma unroll
      for (int ct = 0; ct < 2; ++ct) acc[rt][ct] = (f32x4){0.f, 0.f, 0.f, 0.f};

    // GEMM1: h[u]@Wu + h[v]@Wv
#pragma unroll
    for (int kc = 0; kc < 4; ++kc) {
#pragma unroll
      for (int rt = 0; rt < 4; ++rt) {
        const short8 au = *(const short8*)(&sA[cur][rt * 16 + l15][kc * 32 + quad * 8]);
        const short8 av = *(const short8*)(&sB[cur][rt * 16 + l15][kc * 32 + quad * 8]);
#pragma unroll
        for (int ct = 0; ct < 2; ++ct) {
          acc[rt][ct] = MFMA16(au, wWu[ct][kc], acc[rt][ct]);
          acc[rt][ct] = MFMA16(av, wWv[ct][kc], acc[rt][ct]);
        }
      }
    }
    __syncthreads();  // b1: all waves done reading sA/sB[cur] for GEMM1

    // ep1: t1 = silu(pre + dis*Wdis + b1) -> sA[cur]  (pairwise pk-convert)
#pragma unroll
    for (int rt = 0; rt < 4; ++rt) {
#pragma unroll
      for (int ct = 0; ct < 2; ++ct) {
        const int col = wave * 32 + ct * 16 + l15;
#pragma unroll
        for (int r = 0; r < 4; r += 2) {
          const int row = rt * 16 + quad * 4 + r;
          const float x0 = acc[rt][ct][r] + sDis[cur][row] * vWd[ct] + vb1[ct];
          const float x1 = acc[rt][ct][r + 1] + sDis[cur][row + 1] * vWd[ct] + vb1[ct];
          const unsigned int p = f2b2(silu_f(x0), silu_f(x1));
          sA[cur][row][col] = (unsigned short)p;
          sA[cur][row + 1][col] = (unsigned short)(p >> 16);
        }
      }
    }
    // land prefetched rows into the other buffer
    if (hasNext) {
      if (tid < 64) sDis[nxt][tid] = pfD;
#pragma unroll
      for (int it = 0; it < 4; ++it) {
        const int rr = r0 + it * 16;
        *(uint4*)(&sA[nxt][rr][ch * 8]) = pfA[it];
        *(uint4*)(&sB[nxt][rr][ch * 8]) = pfB[it];
      }
    }
    __syncthreads();  // b2: ep1 + prefetch writes visible

    // GEMM2: t1@W2
#pragma unroll
    for (int rt = 0; rt < 4; ++rt)
#pragma unroll
      for (int ct = 0; ct < 2; ++ct) acc[rt][ct] = (f32x4){0.f, 0.f, 0.f, 0.f};
#pragma unroll
    for (int kc = 0; kc < 4; ++kc) {
#pragma unroll
      for (int rt = 0; rt < 4; ++rt) {
        const short8 a = *(const short8*)(&sA[cur][rt * 16 + l15][kc * 32 + quad * 8]);
#pragma unroll
        for (int ct = 0; ct < 2; ++ct) acc[rt][ct] = MFMA16(a, wW2[ct][kc], acc[rt][ct]);
      }
    }
    // ep2: t2 = silu(acc + b2) -> sB[cur]
#pragma unroll
    for (int rt = 0; rt < 4; ++rt) {
#pragma unroll
      for (int ct = 0; ct < 2; ++ct) {
        const int col = wave * 32 + ct * 16 + l15;
#pragma unroll
        for (int r = 0; r < 4; r += 2) {
          const int row = rt * 16 + quad * 4 + r;
          const unsigned int p = f2b2(silu_f(acc[rt][ct][r] + vb2[ct]),
                                      silu_f(acc[rt][ct][r + 1] + vb2[ct]));
          sB[cur][row][col] = (unsigned short)p;
          sB[cur][row + 1][col] = (unsigned short)(p >> 16);
        }
      }
    }
    __syncthreads();  // b3: ep2 writes visible (GEMM2 done -> sA[cur] dead)

    // GEMM3: t2@W3
#pragma unroll
    for (int rt = 0; rt < 4; ++rt)
#pragma unroll
      for (int ct = 0; ct < 2; ++ct) acc[rt][ct] = (f32x4){0.f, 0.f, 0.f, 0.f};
#pragma unroll
    for (int kc = 0; kc < 4; ++kc) {
#pragma unroll
      for (int rt = 0; rt < 4; ++rt) {
        const short8 a = *(const short8*)(&sB[cur][rt * 16 + l15][kc * 32 + quad * 8]);
#pragma unroll
        for (int ct = 0; ct < 2; ++ct) acc[rt][ct] = MFMA16(a, wW3[ct][kc], acc[rt][ct]);
      }
    }
    // m -> sA[cur] (dead), then cooperative full-row NT stores
#pragma unroll
    for (int rt = 0; rt < 4; ++rt) {
#pragma unroll
      for (int ct = 0; ct < 2; ++ct) {
        const int col = wave * 32 + ct * 16 + l15;
#pragma unroll
        for (int r = 0; r < 4; r += 2) {
          const int row = rt * 16 + quad * 4 + r;
          const unsigned int p = f2b2(acc[rt][ct][r] + vb3[ct],
                                      acc[rt][ct][r + 1] + vb3[ct]);
          sA[cur][row][col] = (unsigned short)p;
          sA[cur][row + 1][col] = (unsigned short)(p >> 16);
        }
      }
    }
    __syncthreads();  // b4: m assembled
#pragma unroll
    for (int it = 0; it < 4; ++it) {
      const int rr = r0 + it * 16;
      __builtin_nontemporal_store(*(const uint4n*)(&sA[cur][rr][ch * 8]),
                                  (uint4n*)(msg + (size_t)(tile * 64 + rr) * H + ch * 8));
    }
  }
}

// ---------------------------------------------------------------------------
// Aggregate chunk c. msg loads NT (round-13 A/B: NT >= normal). list loads
// NORMAL — the address is wave-uniform (start[atom] per-wave), so without
// the NT builtin the compiler can scalarize them to s_load, freeing the
// VMEM queue for msg rows.
// ---------------------------------------------------------------------------
__global__ __launch_bounds__(256)
void aggregate_kernel(const int* __restrict__ start, const int* __restrict__ list,
                      const unsigned short* __restrict__ msg, int eBase,
                      float* __restrict__ af32, unsigned short* __restrict__ aout,
                      int cellBase, int isFirst, int isLast) {
  const int atom = blockIdx.x * 4 + (threadIdx.x >> 6);
  const int lane = threadIdx.x & 63;
  const int s = start[cellBase + atom];
  const int e = start[cellBase + atom + 1];
  float ax = 0.f, ay = 0.f;
  if (!isFirst) {
    const float2 p = *(const float2*)(af32 + (size_t)atom * H + lane * 2);
    ax = p.x; ay = p.y;
  }
  const unsigned int* mp = (const unsigned int*)msg;
  int i = s;
  for (; i + 3 < e; i += 4) {
    const int r0 = list[i] - eBase;
    const int r1 = list[i + 1] - eBase;
    const int r2 = list[i + 2] - eBase;
    const int r3 = list[i + 3] - eBase;
    const unsigned int u0 = __builtin_nontemporal_load(mp + (size_t)r0 * 64 + lane);
    const unsigned int u1 = __builtin_nontemporal_load(mp + (size_t)r1 * 64 + lane);
    const unsigned int u2 = __builtin_nontemporal_load(mp + (size_t)r2 * 64 + lane);
    const unsigned int u3 = __builtin_nontemporal_load(mp + (size_t)r3 * 64 + lane);
    ax += b2f((unsigned short)u0) + b2f((unsigned short)u1) +
          b2f((unsigned short)u2) + b2f((unsigned short)u3);
    ay += b2f((unsigned short)(u0 >> 16)) + b2f((unsigned short)(u1 >> 16)) +
          b2f((unsigned short)(u2 >> 16)) + b2f((unsigned short)(u3 >> 16));
  }
  for (; i < e; ++i) {
    const int r = list[i] - eBase;
    const unsigned int u0 = __builtin_nontemporal_load(mp + (size_t)r * 64 + lane);
    ax += b2f((unsigned short)u0);
    ay += b2f((unsigned short)(u0 >> 16));
  }
  if (isLast) {
    *(unsigned int*)(aout + (size_t)atom * H + lane * 2) = f2b2(ax, ay);
  } else {
    *(float2*)(af32 + (size_t)atom * H + lane * 2) = make_float2(ax, ay);
  }
}

// ---------------------------------------------------------------------------
// Atom update: h_new = h + silu(h@Wh + a1@Wa1 + a2@Wa2 + b1)@W2 + b2
// Row-local -> in-place OK. Fast epilogues (pk-convert + hw-rcp silu).
// ---------------------------------------------------------------------------
__global__ __launch_bounds__(256, 2)
void update_kernel(const unsigned short* __restrict__ hin,
                   const unsigned short* __restrict__ a1, const unsigned short* __restrict__ a2,
                   const unsigned short* __restrict__ pWh, const unsigned short* __restrict__ pWa1,
                   const unsigned short* __restrict__ pWa2, const unsigned short* __restrict__ pWo,
                   const float* __restrict__ b1, const float* __restrict__ b2,
                   unsigned short* __restrict__ hout) {
  __shared__ __attribute__((aligned(16))) unsigned short sH[64][136];
  __shared__ __attribute__((aligned(16))) unsigned short s1[64][136];
  __shared__ __attribute__((aligned(16))) unsigned short s2[64][136];

  const int tid = threadIdx.x;
  const int wave = tid >> 6;
  const int lane = tid & 63;
  const int l15 = lane & 15;
  const int quad = lane >> 4;

  short8 wWh[2][4], wW1[2][4], wW2m[2][4], wWo[2][4];
#pragma unroll
  for (int ct = 0; ct < 2; ++ct) {
#pragma unroll
    for (int kc = 0; kc < 4; ++kc) {
      const int off = (((wave * 2 + ct) * 4 + kc) * 64 + lane) * 8;
      wWh[ct][kc] = *(const short8*)(pWh + off);
      wW1[ct][kc] = *(const short8*)(pWa1 + off);
      wW2m[ct][kc] = *(const short8*)(pWa2 + off);
      wWo[ct][kc] = *(const short8*)(pWo + off);
    }
  }
  float vb1[2], vb2[2];
#pragma unroll
  for (int ct = 0; ct < 2; ++ct) {
    const int col = wave * 32 + ct * 16 + l15;
    vb1[ct] = b1[col]; vb2[ct] = b2[col];
  }

  const int n0 = blockIdx.x * 64;
#pragma unroll
  for (int it = 0; it < 4; ++it) {
    const int r = (tid >> 4) + it * 16;
    const int ch = tid & 15;
    int g = n0 + r; if (g >= NATOM) g = NATOM - 1;
    *(uint4*)(&sH[r][ch * 8]) = *(const uint4*)(hin + (size_t)g * H + ch * 8);
    *(uint4*)(&s1[r][ch * 8]) = *(const uint4*)(a1 + (size_t)g * H + ch * 8);
    *(uint4*)(&s2[r][ch * 8]) = *(const uint4*)(a2 + (size_t)g * H + ch * 8);
  }
  __syncthreads();

  f32x4 acc[4][2];
#pragma unroll
  for (int rt = 0; rt < 4; ++rt)
#pragma unroll
    for (int ct = 0; ct < 2; ++ct) acc[rt][ct] = (f32x4){0.f, 0.f, 0.f, 0.f};

#pragma unroll
  for (int kc = 0; kc < 4; ++kc) {
#pragma unroll
    for (int rt = 0; rt < 4; ++rt) {
      const short8 ah = *(const short8*)(&sH[rt * 16 + l15][kc * 32 + quad * 8]);
      const short8 aa1 = *(const short8*)(&s1[rt * 16 + l15][kc * 32 + quad * 8]);
      const short8 aa2 = *(const short8*)(&s2[rt * 16 + l15][kc * 32 + quad * 8]);
#pragma unroll
      for (int ct = 0; ct < 2; ++ct) {
        acc[rt][ct] = MFMA16(ah, wWh[ct][kc], acc[rt][ct]);
        acc[rt][ct] = MFMA16(aa1, wW1[ct][kc], acc[rt][ct]);
        acc[rt][ct] = MFMA16(aa2, wW2m[ct][kc], acc[rt][ct]);
      }
    }
  }
  __syncthreads();

#pragma unroll
  for (int rt = 0; rt < 4; ++rt) {
#pragma unroll
    for (int ct = 0; ct < 2; ++ct) {
      const int col = wave * 32 + ct * 16 + l15;
#pragma unroll
      for (int r = 0; r < 4; r += 2) {
        const int row = rt * 16 + quad * 4 + r;
        const unsigned int p = f2b2(silu_f(acc[rt][ct][r] + vb1[ct]),
                                    silu_f(acc[rt][ct][r + 1] + vb1[ct]));
        s1[row][col] = (unsigned short)p;
        s1[row + 1][col] = (unsigned short)(p >> 16);
      }
    }
  }
  __syncthreads();

#pragma unroll
  for (int rt = 0; rt < 4; ++rt)
#pragma unroll
    for (int ct = 0; ct < 2; ++ct) acc[rt][ct] = (f32x4){0.f, 0.f, 0.f, 0.f};
#pragma unroll
  for (int kc = 0; kc < 4; ++kc) {
#pragma unroll
    for (int rt = 0; rt < 4; ++rt) {
      const short8 a = *(const short8*)(&s1[rt * 16 + l15][kc * 32 + quad * 8]);
#pragma unroll
      for (int ct = 0; ct < 2; ++ct) acc[rt][ct] = MFMA16(a, wWo[ct][kc], acc[rt][ct]);
    }
  }
  __syncthreads();
#pragma unroll
  for (int rt = 0; rt < 4; ++rt) {
#pragma unroll
    for (int ct = 0; ct < 2; ++ct) {
      const int col = wave * 32 + ct * 16 + l15;
#pragma unroll
      for (int r = 0; r < 4; r += 2) {
        const int row = rt * 16 + quad * 4 + r;
        const float v0 = b2f(sH[row][col]) + acc[rt][ct][r] + vb2[ct];
        const float v1 = b2f(sH[row + 1][col]) + acc[rt][ct][r + 1] + vb2[ct];
        const unsigned int p = f2b2(v0, v1);
        s2[row][col] = (unsigned short)p;
        s2[row + 1][col] = (unsigned short)(p >> 16);
      }
    }
  }
  __syncthreads();
#pragma unroll
  for (int it = 0; it < 4; ++it) {
    const int r = (tid >> 4) + it * 16;
    const int ch = tid & 15;
    const int g = n0 + r;
    if (g < NATOM)
      *(uint4*)(hout + (size_t)g * H + ch * 8) = *(const uint4*)(&s2[r][ch * 8]);
  }
}

// ---------------------------------------------------------------------------
__global__ void out_kernel(const unsigned short* __restrict__ h,
                           const float* __restrict__ outW, const float* __restrict__ outb,
                           float* __restrict__ out) {
  const int atom = blockIdx.x * 4 + (threadIdx.x >> 6);
  const int lane = threadIdx.x & 63;
  float s0 = 0.f, s1 = 0.f, s2 = 0.f;
#pragma unroll
  for (int kk = 0; kk < 2; ++kk) {
    const int k = lane + kk * 64;
    const float hv = b2f(h[(size_t)atom * H + k]);
    s0 += hv * outW[k * 3 + 0];
    s1 += hv * outW[k * 3 + 1];
    s2 += hv * outW[k * 3 + 2];
  }
#pragma unroll
  for (int off = 32; off > 0; off >>= 1) {
    s0 += __shfl_down(s0, off);
    s1 += __shfl_down(s1, off);
    s2 += __shfl_down(s2, off);
  }
  if (lane == 0) {
    out[atom * 3 + 0] = s0 + outb[0];
    out[atom * 3 + 1] = s1 + outb[1];
    out[atom * 3 + 2] = s2 + outb[2];
  }
}

// ---------------------------------------------------------------------------
extern "C" void kernel_launch(void* const* d_in, const int* in_sizes, int n_in,
                              void* d_out, int out_size, void* d_ws, size_t ws_size,
                              hipStream_t stream) {
  const int* atom_num = (const int*)d_in[0];
  const float* dis1 = (const float*)d_in[1];
  const float* dis2 = (const float*)d_in[2];
  const int* id1u = (const int*)d_in[3];
  const int* id1v = (const int*)d_in[4];
  const int* id2u = (const int*)d_in[5];
  const int* id2v = (const int*)d_in[6];
  const float* emb = (const float*)d_in[7];
  const float* Wu = (const float*)d_in[8];
  const float* Wv = (const float*)d_in[9];
  const float* Wdis = (const float*)d_in[10];
  const float* eb1 = (const float*)d_in[11];
  const float* eW2 = (const float*)d_in[12];
  const float* eb2 = (const float*)d_in[13];
  const float* eW3 = (const float*)d_in[14];
  const float* eb3 = (const float*)d_in[15];
  const float* Wh = (const float*)d_in[16];
  const float* Wa1 = (const float*)d_in[17];
  const float* Wa2 = (const float*)d_in[18];
  const float* ub1 = (const float*)d_in[19];
  const float* uW2 = (const float*)d_in[20];
  const float* ub2 = (const float*)d_in[21];
  const float* outW = (const float*)d_in[22];
  const float* outb = (const float*)d_in[23];

  auto pad = [](size_t x) { return (x + 255) & ~(size_t)255; };
  // pick nc (edge chunks) so layout fits ws_size; prefer nc=1 (launch count)
  const int cands[6] = {1, 2, 4, 5, 10, 20};
  int nc = 20;
  for (int k = 0; k < 6; ++k) {
    const int n = cands[k];
    const size_t ncells = (size_t)NATOM * n;
    const size_t msgB = (size_t)(NEDGE / n) * H * 2;
    const size_t scratchB = 4 * ncells * 4 + 8192;
    const size_t ovl = (scratchB > msgB) ? scratchB : msgB;
    const size_t tot = pad(786432) + 3 * pad((size_t)NATOM * H * 2) +
                       (n > 1 ? pad((size_t)NATOM * H * 4) : 0) +
                       2 * pad((ncells + 1) * 4) + 2 * pad((size_t)2 * NEDGE * 4) + ovl;
    if (tot <= ws_size || k == 5) { nc = n; break; }
  }
  const int CE = NEDGE / nc;
  const int tilesPerChunk = CE / 64;
  const int ncells = NATOM * nc;
  const int nparts = (ncells + 1023) / 1024;

  char* ws = (char*)d_ws;
  size_t off = 0;
  auto take = [&](size_t bytes) { char* p = ws + off; off += pad(bytes); return p; };
  unsigned short* pw   = (unsigned short*)take(786432);
  unsigned short* h0   = (unsigned short*)take((size_t)NATOM * H * 2);
  unsigned short* a1   = (unsigned short*)take((size_t)NATOM * H * 2);
  unsigned short* a2   = (unsigned short*)take((size_t)NATOM * H * 2);
  float* af32          = (nc > 1) ? (float*)take((size_t)NATOM * H * 4) : (float*)a1;
  int* start1          = (int*)take(((size_t)ncells + 1) * 4);
  int* start2          = (int*)take(((size_t)ncells + 1) * 4);
  int* list1           = (int*)take((size_t)2 * NEDGE * 4);
  int* list2           = (int*)take((size_t)2 * NEDGE * 4);
  char* ovlRegion      = ws + off;   // msg chunk, overlapped with CSR scratch
  unsigned short* msg  = (unsigned short*)ovlRegion;
  int* deg1            = (int*)ovlRegion;            // dead before edge kernels
  int* deg2            = deg1 + ncells;
  int* cursor1         = deg2 + ncells;
  int* cursor2         = cursor1 + ncells;
  int* part1           = cursor2 + ncells;
  int* part2           = part1 + 1024;

  PackSrc ps;
  for (int i = 0; i < 4; ++i) {
    ps.p[i] = Wu + i * 16384;
    ps.p[4 + i] = Wv + i * 16384;
    ps.p[8 + i] = eW2 + i * 16384;
    ps.p[12 + i] = eW3 + i * 16384;
  }
  for (int j = 0; j < 2; ++j) {
    ps.p[16 + j] = Wh + j * 16384;
    ps.p[18 + j] = Wa1 + j * 16384;
    ps.p[20 + j] = Wa2 + j * 16384;
    ps.p[22 + j] = uW2 + j * 16384;
  }
  repack_kernel<<<24, 256, 0, stream>>>(ps, pw);
  embed_kernel<<<12500, 256, 0, stream>>>(atom_num, emb, h0);

  // CSR build
  {
    const int n4 = (int)(((size_t)2 * ncells * 4 + 15) / 16);  // zero deg1,deg2
    zero_int_kernel<<<(n4 + 255) / 256, 256, 0, stream>>>((int4*)deg1, n4);
    count_kernel<<<NEDGE / 256, 256, 0, stream>>>(id1u, id1v, id2u, id2v, deg1, deg2, CE);
    scan_phase1<<<nparts, 256, 0, stream>>>(deg1, part1, ncells);
    scan_phase2<<<1, 1024, 0, stream>>>(part1, nparts);
    scan_phase3<<<nparts, 256, 0, stream>>>(deg1, part1, start1, cursor1, ncells);
    scan_phase1<<<nparts, 256, 0, stream>>>(deg2, part2, ncells);
    scan_phase2<<<1, 1024, 0, stream>>>(part2, nparts);
    scan_phase3<<<nparts, 256, 0, stream>>>(deg2, part2, start2, cursor2, ncells);
    fill_kernel<<<1024, 256, 0, stream>>>(id1u, id1v, id2u, id2v,
                                          cursor1, cursor2, list1, list2, CE, 4);
  }

  const int upd_grid = (NATOM + 63) / 64;
  const int EDGE_GRID = tilesPerChunk < 512 ? tilesPerChunk : 512;
  const int AGG_GRID = NATOM / 4;

  const unsigned short* pWu_[4] = {pw, pw + 16384, pw + 2 * 16384, pw + 3 * 16384};
  const unsigned short* pWv_[4] = {pw + 4 * 16384, pw + 5 * 16384, pw + 6 * 16384, pw + 7 * 16384};
  const unsigned short* pW2_[4] = {pw + 8 * 16384, pw + 9 * 16384, pw + 10 * 16384, pw + 11 * 16384};
  const unsigned short* pW3_[4] = {pw + 12 * 16384, pw + 13 * 16384, pw + 14 * 16384, pw + 15 * 16384};

  for (int layer = 0; layer < 2; ++layer) {
    for (int set = 0; set < 2; ++set) {
      const int blk = layer * 2 + set;
      const int* eu = set == 0 ? id1u : id2u;
      const int* ev = set == 0 ? id1v : id2v;
      const float* ed = set == 0 ? dis1 : dis2;
      const int* est = set == 0 ? start1 : start2;
      const int* els = set == 0 ? list1 : list2;
      unsigned short* aout = set == 0 ? a1 : a2;
      for (int c = 0; c < nc; ++c) {
        edge_kernel<<<EDGE_GRID, 256, 0, stream>>>(h0, eu, ev, ed,
            pWu_[blk], pWv_[blk], pW2_[blk], pW3_[blk],
            Wdis + blk * H, eb1 + blk * H, eb2 + blk * H, eb3 + blk * H,
            msg, c * CE, tilesPerChunk);
        aggregate_kernel<<<AGG_GRID, 256, 0, stream>>>(est, els, msg, c * CE,
            af32, aout, c * NATOM, c == 0 ? 1 : 0, c == nc - 1 ? 1 : 0);
      }
    }
    update_kernel<<<upd_grid, 256, 0, stream>>>(h0, a1, a2,
        pw + (16 + layer) * 16384, pw + (18 + layer) * 16384,
        pw + (20 + layer) * 16384, pw + (22 + layer) * 16384,
        ub1 + layer * H, ub2 + layer * H, h0);
  }

  out_kernel<<<12500, 256, 0, stream>>>(h0, outW, outb, (float*)d_out);
}

// Round 16
// 1726.637 us; speedup vs baseline: 1.0332x; 1.0332x over previous
//
#include <hip/hip_runtime.h>

#define H 128
#define NATOM 50000
#define NEDGE 800000

typedef __attribute__((ext_vector_type(8))) short short8;
typedef __attribute__((ext_vector_type(4))) float f32x4;
typedef __attribute__((ext_vector_type(4))) unsigned int uint4n;  // NT-store-compatible

#define MFMA16(a, b, c) __builtin_amdgcn_mfma_f32_16x16x32_bf16((a), (b), (c), 0, 0, 0)

__device__ __forceinline__ unsigned short f2b(float f) {
  unsigned int u = __float_as_uint(f);
  unsigned int r = (u + 0x7FFFu + ((u >> 16) & 1u)) >> 16;
  return (unsigned short)r;
}
__device__ __forceinline__ float b2f(unsigned short b) {
  return __uint_as_float(((unsigned int)b) << 16);
}

// Packed f32x2 -> bf16x2 (RNE). gfx950 v_cvt_pk_bf16_f32 = 1 inst vs ~8 for
// two manual RNE converts; guarded so a missing builtin can't break compile.
#if __has_builtin(__builtin_amdgcn_cvt_pk_bf16_f32)
__device__ __forceinline__ unsigned int f2b2(float lo, float hi) {
  typedef __bf16 bf16x2 __attribute__((ext_vector_type(2)));
  bf16x2 r = __builtin_amdgcn_cvt_pk_bf16_f32(lo, hi);
  union { bf16x2 v; unsigned int u; } c;
  c.v = r;
  return c.u;
}
#else
__device__ __forceinline__ unsigned int f2b2(float lo, float hi) {
  return (unsigned int)f2b(lo) | ((unsigned int)f2b(hi) << 16);
}
#endif

// Fast silu: hardware rcp (~1e-5 rel err, far below bf16 lsb).
__device__ __forceinline__ float silu_f(float x) {
  return x * __builtin_amdgcn_rcpf(1.0f + __expf(-x));
}

// ---------------------------------------------------------------------------
// Weight repack: f32 [128][128] row-major -> bf16 MFMA B-fragment layout.
// ---------------------------------------------------------------------------
struct PackSrc { const float* p[24]; };

__global__ void repack_kernel(PackSrc ps, unsigned short* __restrict__ dst) {
  const float* src = ps.p[blockIdx.x];
  unsigned short* d = dst + (size_t)blockIdx.x * 16384;
  for (int s = threadIdx.x; s < 2048; s += 256) {
    const int ct = s >> 8;
    const int kc = (s >> 6) & 3;
    const int lane = s & 63;
    const int r0 = kc * 32 + (lane >> 4) * 8;
    const int col = ct * 16 + (lane & 15);
    uint4 u;
    u.x = f2b2(src[(r0 + 0) * H + col], src[(r0 + 1) * H + col]);
    u.y = f2b2(src[(r0 + 2) * H + col], src[(r0 + 3) * H + col]);
    u.z = f2b2(src[(r0 + 4) * H + col], src[(r0 + 5) * H + col]);
    u.w = f2b2(src[(r0 + 6) * H + col], src[(r0 + 7) * H + col]);
    *(uint4*)(d + s * 8) = u;
  }
}

__global__ void embed_kernel(const int* __restrict__ atom_num, const float* __restrict__ emb,
                             unsigned short* __restrict__ h0) {
  const int idx = blockIdx.x * 256 + threadIdx.x;  // over NATOM*64
  const int n = idx >> 6;
  const int c = (idx & 63) * 2;
  const float* src = emb + (size_t)atom_num[n] * H + c;
  *(unsigned int*)(h0 + (size_t)n * H + c) = f2b2(src[0], src[1]);
}

__global__ void zero_int_kernel(int4* __restrict__ p, int n4) {
  const int i = blockIdx.x * 256 + threadIdx.x;
  if (i < n4) p[i] = make_int4(0, 0, 0, 0);
}

// ---------------------------------------------------------------------------
// CSR build. cell = (e/CE)*NATOM + atom (chunk-major). Built once per launch.
// ---------------------------------------------------------------------------
__global__ void count_kernel(const int* __restrict__ u1, const int* __restrict__ v1,
                             const int* __restrict__ u2, const int* __restrict__ v2,
                             int* __restrict__ deg1, int* __restrict__ deg2,
                             int CE) {
  const int e = blockIdx.x * 256 + threadIdx.x;
  const int cb = (e / CE) * NATOM;
  atomicAdd(deg1 + cb + u1[e], 1);
  atomicAdd(deg1 + cb + v1[e], 1);
  atomicAdd(deg2 + cb + u2[e], 1);
  atomicAdd(deg2 + cb + v2[e], 1);
}

// 3-phase parallel scan.
__global__ void scan_phase1(const int* __restrict__ deg, int* __restrict__ partials,
                            int ncells) {
  __shared__ int sh[256];
  const int t = threadIdx.x;
  const int base = blockIdx.x * 1024 + t * 4;
  int s = 0;
#pragma unroll
  for (int j = 0; j < 4; ++j) { const int i = base + j; if (i < ncells) s += deg[i]; }
  sh[t] = s;
  __syncthreads();
  for (int off = 128; off > 0; off >>= 1) {
    if (t < off) sh[t] += sh[t + off];
    __syncthreads();
  }
  if (t == 0) partials[blockIdx.x] = sh[0];
}

__global__ void scan_phase2(int* __restrict__ partials, int np) {
  __shared__ int sh[1024];
  const int t = threadIdx.x;
  const int v = t < np ? partials[t] : 0;
  sh[t] = v;
  __syncthreads();
  for (int off = 1; off < 1024; off <<= 1) {
    int x = 0;
    if (t >= off) x = sh[t - off];
    __syncthreads();
    sh[t] += x;
    __syncthreads();
  }
  if (t < np) partials[t] = sh[t] - v;  // exclusive
}

__global__ void scan_phase3(const int* __restrict__ deg, const int* __restrict__ partials,
                            int* __restrict__ start, int* __restrict__ cursor, int ncells) {
  __shared__ int sh[256];
  const int t = threadIdx.x;
  const int base = blockIdx.x * 1024 + t * 4;
  int v[4];
  int s = 0;
#pragma unroll
  for (int j = 0; j < 4; ++j) {
    const int i = base + j;
    v[j] = (i < ncells) ? deg[i] : 0;
    s += v[j];
  }
  sh[t] = s;
  __syncthreads();
  const int own = s;
  for (int off = 1; off < 256; off <<= 1) {
    int x = 0;
    if (t >= off) x = sh[t - off];
    __syncthreads();
    sh[t] += x;
    __syncthreads();
  }
  int o = partials[blockIdx.x] + sh[t] - own;
#pragma unroll
  for (int j = 0; j < 4; ++j) {
    const int i = base + j;
    if (i < ncells) {
      start[i] = o;
      cursor[i] = o;
      o += v[j];
      if (i == ncells - 1) start[ncells] = o;
    }
  }
}

// Range-bucketed fill with NT id loads (round-14 best config: npass=8).
__global__ void fill_kernel(const int* __restrict__ u1, const int* __restrict__ v1,
                            const int* __restrict__ u2, const int* __restrict__ v2,
                            int* __restrict__ cur1, int* __restrict__ cur2,
                            int* __restrict__ list1, int* __restrict__ list2,
                            int CE, int npass) {
  const int apb = (NATOM + npass - 1) / npass;
  for (int p = 0; p < npass; ++p) {
    const int lo = p * apb, hi = lo + apb;
    for (int e = blockIdx.x * 256 + threadIdx.x; e < NEDGE; e += gridDim.x * 256) {
      const int cb = (e / CE) * NATOM;
      int a;
      a = __builtin_nontemporal_load(u1 + e);
      if (a >= lo && a < hi) { const int s = atomicAdd(cur1 + cb + a, 1); list1[s] = e; }
      a = __builtin_nontemporal_load(v1 + e);
      if (a >= lo && a < hi) { const int s = atomicAdd(cur1 + cb + a, 1); list1[s] = e; }
      a = __builtin_nontemporal_load(u2 + e);
      if (a >= lo && a < hi) { const int s = atomicAdd(cur2 + cb + a, 1); list2[s] = e; }
      a = __builtin_nontemporal_load(v2 + e);
      if (a >= lo && a < hi) { const int s = atomicAdd(cur2 + cb + a, 1); list2[s] = e; }
    }
  }
}

// ---------------------------------------------------------------------------
// Fused edge MLP — round-7 structure + fast epilogues (measured 250us,
// VALUBusy 33.5, MfmaUtil 18; residual ~48% stall is the 4-barrier K-loop's
// structural drain at 2 blocks/CU — 5 restructures all regressed).
// ---------------------------------------------------------------------------
__global__ __launch_bounds__(256, 2)
void edge_kernel(const unsigned short* __restrict__ h,
                 const int* __restrict__ idu, const int* __restrict__ idv,
                 const float* __restrict__ dis,
                 const unsigned short* __restrict__ pWu, const unsigned short* __restrict__ pWv,
                 const unsigned short* __restrict__ pW2, const unsigned short* __restrict__ pW3,
                 const float* __restrict__ Wdis, const float* __restrict__ b1,
                 const float* __restrict__ b2, const float* __restrict__ b3,
                 unsigned short* __restrict__ msg, int eBase, int nTiles) {
  __shared__ __attribute__((aligned(16))) unsigned short sA[2][64][136];
  __shared__ __attribute__((aligned(16))) unsigned short sB[2][64][136];
  __shared__ float sDis[2][64];

  const int tid = threadIdx.x;
  const int wave = tid >> 6;
  const int lane = tid & 63;
  const int l15 = lane & 15;
  const int quad = lane >> 4;

  short8 wWu[2][4], wWv[2][4], wW2[2][4], wW3[2][4];
#pragma unroll
  for (int ct = 0; ct < 2; ++ct) {
#pragma unroll
    for (int kc = 0; kc < 4; ++kc) {
      const int off = (((wave * 2 + ct) * 4 + kc) * 64 + lane) * 8;
      wWu[ct][kc] = *(const short8*)(pWu + off);
      wWv[ct][kc] = *(const short8*)(pWv + off);
      wW2[ct][kc] = *(const short8*)(pW2 + off);
      wW3[ct][kc] = *(const short8*)(pW3 + off);
    }
  }
  float vWd[2], vb1[2], vb2[2], vb3[2];
#pragma unroll
  for (int ct = 0; ct < 2; ++ct) {
    const int col = wave * 32 + ct * 16 + l15;
    vWd[ct] = Wdis[col]; vb1[ct] = b1[col]; vb2[ct] = b2[col]; vb3[ct] = b3[col];
  }

  const int stride = gridDim.x;
  const int r0 = tid >> 4;
  const int ch = tid & 15;
  int tile = blockIdx.x;
  int cur = 0;

  if (tile < nTiles) {  // prologue: stage tile -> buf0
    const int e0 = eBase + tile * 64;
    if (tid < 64) sDis[0][tid] = dis[e0 + tid];
#pragma unroll
    for (int it = 0; it < 4; ++it) {
      const int rr = r0 + it * 16;
      *(uint4*)(&sA[0][rr][ch * 8]) = *(const uint4*)(h + (size_t)idu[e0 + rr] * H + ch * 8);
      *(uint4*)(&sB[0][rr][ch * 8]) = *(const uint4*)(h + (size_t)idv[e0 + rr] * H + ch * 8);
    }
  }
  __syncthreads();

  for (; tile < nTiles; tile += stride, cur ^= 1) {
    const int nxt = cur ^ 1;
    const int tileN = tile + stride;
    const bool hasNext = tileN < nTiles;
    uint4 pfA[4], pfB[4];
    float pfD = 0.f;
    if (hasNext) {  // issue next tile's gathers (landed after b1)
      const int e0n = eBase + tileN * 64;
      if (tid < 64) pfD = dis[e0n + tid];
#pragma unroll
      for (int it = 0; it < 4; ++it) {
        const int rr = r0 + it * 16;
        pfA[it] = *(const uint4*)(h + (size_t)idu[e0n + rr] * H + ch * 8);
        pfB[it] = *(const uint4*)(h + (size_t)idv[e0n + rr] * H + ch * 8);
      }
    }

    f32x4 acc[4][2];
#pragma unroll
    for (int rt = 0; rt < 4; ++rt)
#pragma unroll
      for (int ct = 0; ct < 2; ++ct) acc[rt][ct] = (f32x4){0.f, 0.f, 0.f, 0.f};

    // GEMM1: h[u]@Wu + h[v]@Wv
#pragma unroll
    for (int kc = 0; kc < 4; ++kc) {
#pragma unroll
      for (int rt = 0; rt < 4; ++rt) {
        const short8 au = *(const short8*)(&sA[cur][rt * 16 + l15][kc * 32 + quad * 8]);
        const short8 av = *(const short8*)(&sB[cur][rt * 16 + l15][kc * 32 + quad * 8]);
#pragma unroll
        for (int ct = 0; ct < 2; ++ct) {
          acc[rt][ct] = MFMA16(au, wWu[ct][kc], acc[rt][ct]);
          acc[rt][ct] = MFMA16(av, wWv[ct][kc], acc[rt][ct]);
        }
      }
    }
    __syncthreads();  // b1: all waves done reading sA/sB[cur] for GEMM1

    // ep1: t1 = silu(pre + dis*Wdis + b1) -> sA[cur]  (pairwise pk-convert)
#pragma unroll
    for (int rt = 0; rt < 4; ++rt) {
#pragma unroll
      for (int ct = 0; ct < 2; ++ct) {
        const int col = wave * 32 + ct * 16 + l15;
#pragma unroll
        for (int r = 0; r < 4; r += 2) {
          const int row = rt * 16 + quad * 4 + r;
          const float x0 = acc[rt][ct][r] + sDis[cur][row] * vWd[ct] + vb1[ct];
          const float x1 = acc[rt][ct][r + 1] + sDis[cur][row + 1] * vWd[ct] + vb1[ct];
          const unsigned int p = f2b2(silu_f(x0), silu_f(x1));
          sA[cur][row][col] = (unsigned short)p;
          sA[cur][row + 1][col] = (unsigned short)(p >> 16);
        }
      }
    }
    // land prefetched rows into the other buffer
    if (hasNext) {
      if (tid < 64) sDis[nxt][tid] = pfD;
#pragma unroll
      for (int it = 0; it < 4; ++it) {
        const int rr = r0 + it * 16;
        *(uint4*)(&sA[nxt][rr][ch * 8]) = pfA[it];
        *(uint4*)(&sB[nxt][rr][ch * 8]) = pfB[it];
      }
    }
    __syncthreads();  // b2: ep1 + prefetch writes visible

    // GEMM2: t1@W2
#pragma unroll
    for (int rt = 0; rt < 4; ++rt)
#pragma unroll
      for (int ct = 0; ct < 2; ++ct) acc[rt][ct] = (f32x4){0.f, 0.f, 0.f, 0.f};
#pragma unroll
    for (int kc = 0; kc < 4; ++kc) {
#pragma unroll
      for (int rt = 0; rt < 4; ++rt) {
        const short8 a = *(const short8*)(&sA[cur][rt * 16 + l15][kc * 32 + quad * 8]);
#pragma unroll
        for (int ct = 0; ct < 2; ++ct) acc[rt][ct] = MFMA16(a, wW2[ct][kc], acc[rt][ct]);
      }
    }
    // ep2: t2 = silu(acc + b2) -> sB[cur]
#pragma unroll
    for (int rt = 0; rt < 4; ++rt) {
#pragma unroll
      for (int ct = 0; ct < 2; ++ct) {
        const int col = wave * 32 + ct * 16 + l15;
#pragma unroll
        for (int r = 0; r < 4; r += 2) {
          const int row = rt * 16 + quad * 4 + r;
          const unsigned int p = f2b2(silu_f(acc[rt][ct][r] + vb2[ct]),
                                      silu_f(acc[rt][ct][r + 1] + vb2[ct]));
          sB[cur][row][col] = (unsigned short)p;
          sB[cur][row + 1][col] = (unsigned short)(p >> 16);
        }
      }
    }
    __syncthreads();  // b3: ep2 writes visible (GEMM2 done -> sA[cur] dead)

    // GEMM3: t2@W3
#pragma unroll
    for (int rt = 0; rt < 4; ++rt)
#pragma unroll
      for (int ct = 0; ct < 2; ++ct) acc[rt][ct] = (f32x4){0.f, 0.f, 0.f, 0.f};
#pragma unroll
    for (int kc = 0; kc < 4; ++kc) {
#pragma unroll
      for (int rt = 0; rt < 4; ++rt) {
        const short8 a = *(const short8*)(&sB[cur][rt * 16 + l15][kc * 32 + quad * 8]);
#pragma unroll
        for (int ct = 0; ct < 2; ++ct) acc[rt][ct] = MFMA16(a, wW3[ct][kc], acc[rt][ct]);
      }
    }
    // m -> sA[cur] (dead), then cooperative full-row NT stores
#pragma unroll
    for (int rt = 0; rt < 4; ++rt) {
#pragma unroll
      for (int ct = 0; ct < 2; ++ct) {
        const int col = wave * 32 + ct * 16 + l15;
#pragma unroll
        for (int r = 0; r < 4; r += 2) {
          const int row = rt * 16 + quad * 4 + r;
          const unsigned int p = f2b2(acc[rt][ct][r] + vb3[ct],
                                      acc[rt][ct][r + 1] + vb3[ct]);
          sA[cur][row][col] = (unsigned short)p;
          sA[cur][row + 1][col] = (unsigned short)(p >> 16);
        }
      }
    }
    __syncthreads();  // b4: m assembled
#pragma unroll
    for (int it = 0; it < 4; ++it) {
      const int rr = r0 + it * 16;
      __builtin_nontemporal_store(*(const uint4n*)(&sA[cur][rr][ch * 8]),
                                  (uint4n*)(msg + (size_t)(tile * 64 + rr) * H + ch * 8));
    }
  }
}

// ---------------------------------------------------------------------------
// Aggregate chunk c. Latency-bound random gather: 8-deep unroll keeps 8
// msg-row loads (8 x 256B) in flight per wave (was 4). NT list+msg loads
// (round-14 best).
// ---------------------------------------------------------------------------
__global__ __launch_bounds__(256)
void aggregate_kernel(const int* __restrict__ start, const int* __restrict__ list,
                      const unsigned short* __restrict__ msg, int eBase,
                      float* __restrict__ af32, unsigned short* __restrict__ aout,
                      int cellBase, int isFirst, int isLast) {
  const int atom = blockIdx.x * 4 + (threadIdx.x >> 6);
  const int lane = threadIdx.x & 63;
  const int s = start[cellBase + atom];
  const int e = start[cellBase + atom + 1];
  float ax = 0.f, ay = 0.f;
  if (!isFirst) {
    const float2 p = *(const float2*)(af32 + (size_t)atom * H + lane * 2);
    ax = p.x; ay = p.y;
  }
  const unsigned int* mp = (const unsigned int*)msg;
  int i = s;
  for (; i + 7 < e; i += 8) {
    int r[8];
#pragma unroll
    for (int j = 0; j < 8; ++j) r[j] = __builtin_nontemporal_load(list + i + j) - eBase;
    unsigned int u[8];
#pragma unroll
    for (int j = 0; j < 8; ++j) u[j] = __builtin_nontemporal_load(mp + (size_t)r[j] * 64 + lane);
#pragma unroll
    for (int j = 0; j < 8; ++j) {
      ax += b2f((unsigned short)u[j]);
      ay += b2f((unsigned short)(u[j] >> 16));
    }
  }
  for (; i < e; ++i) {
    const int r = __builtin_nontemporal_load(list + i) - eBase;
    const unsigned int u0 = __builtin_nontemporal_load(mp + (size_t)r * 64 + lane);
    ax += b2f((unsigned short)u0);
    ay += b2f((unsigned short)(u0 >> 16));
  }
  if (isLast) {
    *(unsigned int*)(aout + (size_t)atom * H + lane * 2) = f2b2(ax, ay);
  } else {
    *(float2*)(af32 + (size_t)atom * H + lane * 2) = make_float2(ax, ay);
  }
}

// ---------------------------------------------------------------------------
// Atom update: h_new = h + silu(h@Wh + a1@Wa1 + a2@Wa2 + b1)@W2 + b2
// Row-local -> in-place OK. Fast epilogues (pk-convert + hw-rcp silu).
// ---------------------------------------------------------------------------
__global__ __launch_bounds__(256, 2)
void update_kernel(const unsigned short* __restrict__ hin,
                   const unsigned short* __restrict__ a1, const unsigned short* __restrict__ a2,
                   const unsigned short* __restrict__ pWh, const unsigned short* __restrict__ pWa1,
                   const unsigned short* __restrict__ pWa2, const unsigned short* __restrict__ pWo,
                   const float* __restrict__ b1, const float* __restrict__ b2,
                   unsigned short* __restrict__ hout) {
  __shared__ __attribute__((aligned(16))) unsigned short sH[64][136];
  __shared__ __attribute__((aligned(16))) unsigned short s1[64][136];
  __shared__ __attribute__((aligned(16))) unsigned short s2[64][136];

  const int tid = threadIdx.x;
  const int wave = tid >> 6;
  const int lane = tid & 63;
  const int l15 = lane & 15;
  const int quad = lane >> 4;

  short8 wWh[2][4], wW1[2][4], wW2m[2][4], wWo[2][4];
#pragma unroll
  for (int ct = 0; ct < 2; ++ct) {
#pragma unroll
    for (int kc = 0; kc < 4; ++kc) {
      const int off = (((wave * 2 + ct) * 4 + kc) * 64 + lane) * 8;
      wWh[ct][kc] = *(const short8*)(pWh + off);
      wW1[ct][kc] = *(const short8*)(pWa1 + off);
      wW2m[ct][kc] = *(const short8*)(pWa2 + off);
      wWo[ct][kc] = *(const short8*)(pWo + off);
    }
  }
  float vb1[2], vb2[2];
#pragma unroll
  for (int ct = 0; ct < 2; ++ct) {
    const int col = wave * 32 + ct * 16 + l15;
    vb1[ct] = b1[col]; vb2[ct] = b2[col];
  }

  const int n0 = blockIdx.x * 64;
#pragma unroll
  for (int it = 0; it < 4; ++it) {
    const int r = (tid >> 4) + it * 16;
    const int ch = tid & 15;
    int g = n0 + r; if (g >= NATOM) g = NATOM - 1;
    *(uint4*)(&sH[r][ch * 8]) = *(const uint4*)(hin + (size_t)g * H + ch * 8);
    *(uint4*)(&s1[r][ch * 8]) = *(const uint4*)(a1 + (size_t)g * H + ch * 8);
    *(uint4*)(&s2[r][ch * 8]) = *(const uint4*)(a2 + (size_t)g * H + ch * 8);
  }
  __syncthreads();

  f32x4 acc[4][2];
#pragma unroll
  for (int rt = 0; rt < 4; ++rt)
#pragma unroll
    for (int ct = 0; ct < 2; ++ct) acc[rt][ct] = (f32x4){0.f, 0.f, 0.f, 0.f};

#pragma unroll
  for (int kc = 0; kc < 4; ++kc) {
#pragma unroll
    for (int rt = 0; rt < 4; ++rt) {
      const short8 ah = *(const short8*)(&sH[rt * 16 + l15][kc * 32 + quad * 8]);
      const short8 aa1 = *(const short8*)(&s1[rt * 16 + l15][kc * 32 + quad * 8]);
      const short8 aa2 = *(const short8*)(&s2[rt * 16 + l15][kc * 32 + quad * 8]);
#pragma unroll
      for (int ct = 0; ct < 2; ++ct) {
        acc[rt][ct] = MFMA16(ah, wWh[ct][kc], acc[rt][ct]);
        acc[rt][ct] = MFMA16(aa1, wW1[ct][kc], acc[rt][ct]);
        acc[rt][ct] = MFMA16(aa2, wW2m[ct][kc], acc[rt][ct]);
      }
    }
  }
  __syncthreads();

#pragma unroll
  for (int rt = 0; rt < 4; ++rt) {
#pragma unroll
    for (int ct = 0; ct < 2; ++ct) {
      const int col = wave * 32 + ct * 16 + l15;
#pragma unroll
      for (int r = 0; r < 4; r += 2) {
        const int row = rt * 16 + quad * 4 + r;
        const unsigned int p = f2b2(silu_f(acc[rt][ct][r] + vb1[ct]),
                                    silu_f(acc[rt][ct][r + 1] + vb1[ct]));
        s1[row][col] = (unsigned short)p;
        s1[row + 1][col] = (unsigned short)(p >> 16);
      }
    }
  }
  __syncthreads();

#pragma unroll
  for (int rt = 0; rt < 4; ++rt)
#pragma unroll
    for (int ct = 0; ct < 2; ++ct) acc[rt][ct] = (f32x4){0.f, 0.f, 0.f, 0.f};
#pragma unroll
  for (int kc = 0; kc < 4; ++kc) {
#pragma unroll
    for (int rt = 0; rt < 4; ++rt) {
      const short8 a = *(const short8*)(&s1[rt * 16 + l15][kc * 32 + quad * 8]);
#pragma unroll
      for (int ct = 0; ct < 2; ++ct) acc[rt][ct] = MFMA16(a, wWo[ct][kc], acc[rt][ct]);
    }
  }
  __syncthreads();
#pragma unroll
  for (int rt = 0; rt < 4; ++rt) {
#pragma unroll
    for (int ct = 0; ct < 2; ++ct) {
      const int col = wave * 32 + ct * 16 + l15;
#pragma unroll
      for (int r = 0; r < 4; r += 2) {
        const int row = rt * 16 + quad * 4 + r;
        const float v0 = b2f(sH[row][col]) + acc[rt][ct][r] + vb2[ct];
        const float v1 = b2f(sH[row + 1][col]) + acc[rt][ct][r + 1] + vb2[ct];
        const unsigned int p = f2b2(v0, v1);
        s2[row][col] = (unsigned short)p;
        s2[row + 1][col] = (unsigned short)(p >> 16);
      }
    }
  }
  __syncthreads();
#pragma unroll
  for (int it = 0; it < 4; ++it) {
    const int r = (tid >> 4) + it * 16;
    const int ch = tid & 15;
    const int g = n0 + r;
    if (g < NATOM)
      *(uint4*)(hout + (size_t)g * H + ch * 8) = *(const uint4*)(&s2[r][ch * 8]);
  }
}

// ---------------------------------------------------------------------------
__global__ void out_kernel(const unsigned short* __restrict__ h,
                           const float* __restrict__ outW, const float* __restrict__ outb,
                           float* __restrict__ out) {
  const int atom = blockIdx.x * 4 + (threadIdx.x >> 6);
  const int lane = threadIdx.x & 63;
  float s0 = 0.f, s1 = 0.f, s2 = 0.f;
#pragma unroll
  for (int kk = 0; kk < 2; ++kk) {
    const int k = lane + kk * 64;
    const float hv = b2f(h[(size_t)atom * H + k]);
    s0 += hv * outW[k * 3 + 0];
    s1 += hv * outW[k * 3 + 1];
    s2 += hv * outW[k * 3 + 2];
  }
#pragma unroll
  for (int off = 32; off > 0; off >>= 1) {
    s0 += __shfl_down(s0, off);
    s1 += __shfl_down(s1, off);
    s2 += __shfl_down(s2, off);
  }
  if (lane == 0) {
    out[atom * 3 + 0] = s0 + outb[0];
    out[atom * 3 + 1] = s1 + outb[1];
    out[atom * 3 + 2] = s2 + outb[2];
  }
}

// ---------------------------------------------------------------------------
extern "C" void kernel_launch(void* const* d_in, const int* in_sizes, int n_in,
                              void* d_out, int out_size, void* d_ws, size_t ws_size,
                              hipStream_t stream) {
  const int* atom_num = (const int*)d_in[0];
  const float* dis1 = (const float*)d_in[1];
  const float* dis2 = (const float*)d_in[2];
  const int* id1u = (const int*)d_in[3];
  const int* id1v = (const int*)d_in[4];
  const int* id2u = (const int*)d_in[5];
  const int* id2v = (const int*)d_in[6];
  const float* emb = (const float*)d_in[7];
  const float* Wu = (const float*)d_in[8];
  const float* Wv = (const float*)d_in[9];
  const float* Wdis = (const float*)d_in[10];
  const float* eb1 = (const float*)d_in[11];
  const float* eW2 = (const float*)d_in[12];
  const float* eb2 = (const float*)d_in[13];
  const float* eW3 = (const float*)d_in[14];
  const float* eb3 = (const float*)d_in[15];
  const float* Wh = (const float*)d_in[16];
  const float* Wa1 = (const float*)d_in[17];
  const float* Wa2 = (const float*)d_in[18];
  const float* ub1 = (const float*)d_in[19];
  const float* uW2 = (const float*)d_in[20];
  const float* ub2 = (const float*)d_in[21];
  const float* outW = (const float*)d_in[22];
  const float* outb = (const float*)d_in[23];

  auto pad = [](size_t x) { return (x + 255) & ~(size_t)255; };
  // pick nc (edge chunks) so layout fits ws_size; prefer nc=1 (launch count)
  const int cands[6] = {1, 2, 4, 5, 10, 20};
  int nc = 20;
  for (int k = 0; k < 6; ++k) {
    const int n = cands[k];
    const size_t ncells = (size_t)NATOM * n;
    const size_t msgB = (size_t)(NEDGE / n) * H * 2;
    const size_t scratchB = 4 * ncells * 4 + 8192;
    const size_t ovl = (scratchB > msgB) ? scratchB : msgB;
    const size_t tot = pad(786432) + 3 * pad((size_t)NATOM * H * 2) +
                       (n > 1 ? pad((size_t)NATOM * H * 4) : 0) +
                       2 * pad((ncells + 1) * 4) + 2 * pad((size_t)2 * NEDGE * 4) + ovl;
    if (tot <= ws_size || k == 5) { nc = n; break; }
  }
  const int CE = NEDGE / nc;
  const int tilesPerChunk = CE / 64;
  const int ncells = NATOM * nc;
  const int nparts = (ncells + 1023) / 1024;

  char* ws = (char*)d_ws;
  size_t off = 0;
  auto take = [&](size_t bytes) { char* p = ws + off; off += pad(bytes); return p; };
  unsigned short* pw   = (unsigned short*)take(786432);
  unsigned short* h0   = (unsigned short*)take((size_t)NATOM * H * 2);
  unsigned short* a1   = (unsigned short*)take((size_t)NATOM * H * 2);
  unsigned short* a2   = (unsigned short*)take((size_t)NATOM * H * 2);
  float* af32          = (nc > 1) ? (float*)take((size_t)NATOM * H * 4) : (float*)a1;
  int* start1          = (int*)take(((size_t)ncells + 1) * 4);
  int* start2          = (int*)take(((size_t)ncells + 1) * 4);
  int* list1           = (int*)take((size_t)2 * NEDGE * 4);
  int* list2           = (int*)take((size_t)2 * NEDGE * 4);
  char* ovlRegion      = ws + off;   // msg chunk, overlapped with CSR scratch
  unsigned short* msg  = (unsigned short*)ovlRegion;
  int* deg1            = (int*)ovlRegion;            // dead before edge kernels
  int* deg2            = deg1 + ncells;
  int* cursor1         = deg2 + ncells;
  int* cursor2         = cursor1 + ncells;
  int* part1           = cursor2 + ncells;
  int* part2           = part1 + 1024;

  PackSrc ps;
  for (int i = 0; i < 4; ++i) {
    ps.p[i] = Wu + i * 16384;
    ps.p[4 + i] = Wv + i * 16384;
    ps.p[8 + i] = eW2 + i * 16384;
    ps.p[12 + i] = eW3 + i * 16384;
  }
  for (int j = 0; j < 2; ++j) {
    ps.p[16 + j] = Wh + j * 16384;
    ps.p[18 + j] = Wa1 + j * 16384;
    ps.p[20 + j] = Wa2 + j * 16384;
    ps.p[22 + j] = uW2 + j * 16384;
  }
  repack_kernel<<<24, 256, 0, stream>>>(ps, pw);
  embed_kernel<<<12500, 256, 0, stream>>>(atom_num, emb, h0);

  // CSR build
  {
    const int n4 = (int)(((size_t)2 * ncells * 4 + 15) / 16);  // zero deg1,deg2
    zero_int_kernel<<<(n4 + 255) / 256, 256, 0, stream>>>((int4*)deg1, n4);
    count_kernel<<<NEDGE / 256, 256, 0, stream>>>(id1u, id1v, id2u, id2v, deg1, deg2, CE);
    scan_phase1<<<nparts, 256, 0, stream>>>(deg1, part1, ncells);
    scan_phase2<<<1, 1024, 0, stream>>>(part1, nparts);
    scan_phase3<<<nparts, 256, 0, stream>>>(deg1, part1, start1, cursor1, ncells);
    scan_phase1<<<nparts, 256, 0, stream>>>(deg2, part2, ncells);
    scan_phase2<<<1, 1024, 0, stream>>>(part2, nparts);
    scan_phase3<<<nparts, 256, 0, stream>>>(deg2, part2, start2, cursor2, ncells);
    fill_kernel<<<1024, 256, 0, stream>>>(id1u, id1v, id2u, id2v,
                                          cursor1, cursor2, list1, list2, CE, 8);
  }

  const int upd_grid = (NATOM + 63) / 64;
  const int EDGE_GRID = tilesPerChunk < 512 ? tilesPerChunk : 512;
  const int AGG_GRID = NATOM / 4;

  const unsigned short* pWu_[4] = {pw, pw + 16384, pw + 2 * 16384, pw + 3 * 16384};
  const unsigned short* pWv_[4] = {pw + 4 * 16384, pw + 5 * 16384, pw + 6 * 16384, pw + 7 * 16384};
  const unsigned short* pW2_[4] = {pw + 8 * 16384, pw + 9 * 16384, pw + 10 * 16384, pw + 11 * 16384};
  const unsigned short* pW3_[4] = {pw + 12 * 16384, pw + 13 * 16384, pw + 14 * 16384, pw + 15 * 16384};

  for (int layer = 0; layer < 2; ++layer) {
    for (int set = 0; set < 2; ++set) {
      const int blk = layer * 2 + set;
      const int* eu = set == 0 ? id1u : id2u;
      const int* ev = set == 0 ? id1v : id2v;
      const float* ed = set == 0 ? dis1 : dis2;
      const int* est = set == 0 ? start1 : start2;
      const int* els = set == 0 ? list1 : list2;
      unsigned short* aout = set == 0 ? a1 : a2;
      for (int c = 0; c < nc; ++c) {
        edge_kernel<<<EDGE_GRID, 256, 0, stream>>>(h0, eu, ev, ed,
            pWu_[blk], pWv_[blk], pW2_[blk], pW3_[blk],
            Wdis + blk * H, eb1 + blk * H, eb2 + blk * H, eb3 + blk * H,
            msg, c * CE, tilesPerChunk);
        aggregate_kernel<<<AGG_GRID, 256, 0, stream>>>(est, els, msg, c * CE,
            af32, aout, c * NATOM, c == 0 ? 1 : 0, c == nc - 1 ? 1 : 0);
      }
    }
    update_kernel<<<upd_grid, 256, 0, stream>>>(h0, a1, a2,
        pw + (16 + layer) * 16384, pw + (18 + layer) * 16384,
        pw + (20 + layer) * 16384, pw + (22 + layer) * 16384,
        ub1 + layer * H, ub2 + layer * H, h0);
  }

  out_kernel<<<12500, 256, 0, stream>>>(h0, outW, outb, (float*)d_out);
}